// Round 7
// baseline (217.170 us; speedup 1.0000x reference)
//
#include <hip/hip_runtime.h>

#define N_FEAT 128
#define N_CLS 64

// 1) degree histogram over dst + per-edge rank (coalesced store, 1 atomic/edge)
__global__ __launch_bounds__(256) void k_rank(const int* __restrict__ dst, int ne,
                                              int* __restrict__ deg, int* __restrict__ rank) {
    int i = blockIdx.x * blockDim.x + threadIdx.x;
    if (i < ne) rank[i] = atomicAdd(&deg[dst[i]], 1);
}

// 2a) per-block exclusive scan of deg (256 elems/block), emit block sums
__global__ __launch_bounds__(256) void k_scan1(const int* __restrict__ deg, int n,
                                               int* __restrict__ offtmp, int* __restrict__ bsum) {
    __shared__ int s[256];
    int t = threadIdx.x;
    int i = blockIdx.x * 256 + t;
    int v = (i < n) ? deg[i] : 0;
    s[t] = v;
    __syncthreads();
    for (int d = 1; d < 256; d <<= 1) {
        int u = (t >= d) ? s[t - d] : 0;
        __syncthreads();
        s[t] += u;
        __syncthreads();
    }
    if (i < n) offtmp[i] = s[t] - v;  // exclusive
    if (t == 255) bsum[blockIdx.x] = s[255];
}

// 2b) single tiny block: exclusive scan of block sums (nb <= 1024)
__global__ __launch_bounds__(1024) void k_scan2(int* __restrict__ bsum, int nb) {
    __shared__ int s[1024];
    int t = threadIdx.x;
    int v = (t < nb) ? bsum[t] : 0;
    s[t] = v;
    __syncthreads();
    for (int d = 1; d < 1024; d <<= 1) {
        int u = (t >= d) ? s[t - d] : 0;
        __syncthreads();
        s[t] += u;
        __syncthreads();
    }
    if (t < nb) bsum[t] = s[t] - v;  // exclusive
}

// 2c) finalize: off = offtmp + block offset; nrm = rsqrt(max(deg,1))
__global__ __launch_bounds__(256) void k_scan3(const int* __restrict__ deg,
                                               const int* __restrict__ offtmp,
                                               const int* __restrict__ bsum, int n, int ne,
                                               int* __restrict__ off, float* __restrict__ nrm) {
    int i = blockIdx.x * 256 + threadIdx.x;
    if (i < n) {
        off[i] = offtmp[i] + bsum[blockIdx.x];
        nrm[i] = rsqrtf(fmaxf((float)deg[i], 1.0f));
    }
    if (i == 0) off[n] = ne;  // total edge count is known
}

// 3) atomic-free scatter: esrc[off[dst] + rank] = src
__global__ __launch_bounds__(256) void k_scatter(const int* __restrict__ src,
                                                 const int* __restrict__ dst,
                                                 const int* __restrict__ rank, int ne,
                                                 const int* __restrict__ off,
                                                 int* __restrict__ esrc) {
    int i = blockIdx.x * blockDim.x + threadIdx.x;
    if (i < ne) {
        esrc[off[dst[i]] + rank[i]] = src[i];
    }
}

// 4) Y[node] = (X[node] * nrm[node]) @ W   -- register-resident-W DGEMV.
//    lane = output column (N_CLS == 64 == wave width). Each lane holds its W
//    column in 128 VGPRs (loaded once, coalesced). Wave processes 16 nodes;
//    node index is wave-uniform -> X row reads are uniform-address s_load
//    broadcasts. Inner loop: 4 independent 128-FMA chains. No LDS, no barriers.
#define NODES_PER_WAVE 16
__global__ __launch_bounds__(256, 3) void k_gemm(const float* __restrict__ X,
                                                 const float* __restrict__ W,
                                                 const float* __restrict__ nrm,
                                                 float* __restrict__ Y, int n) {
    int lane = threadIdx.x & 63;
    int gwave = __builtin_amdgcn_readfirstlane(
        (int)((blockIdx.x * (size_t)blockDim.x + threadIdx.x) >> 6));
    int base = gwave * NODES_PER_WAVE;
    if (base >= n) return;

    // W column for this lane: w[k] = W[k][lane] (128 coalesced 256B loads/wave)
    float w[N_FEAT];
#pragma unroll
    for (int k = 0; k < N_FEAT; ++k) w[k] = W[(size_t)k * N_CLS + lane];

    int nend = min(base + NODES_PER_WAVE, n);
    int node = base;
    for (; node + 3 < nend; node += 4) {
        const float* x0 = X + (size_t)(node + 0) * N_FEAT;  // uniform addresses
        const float* x1 = X + (size_t)(node + 1) * N_FEAT;
        const float* x2 = X + (size_t)(node + 2) * N_FEAT;
        const float* x3 = X + (size_t)(node + 3) * N_FEAT;
        float a0 = 0.f, a1 = 0.f, a2 = 0.f, a3 = 0.f;
#pragma unroll
        for (int k = 0; k < N_FEAT; ++k) {
            a0 = fmaf(x0[k], w[k], a0);
            a1 = fmaf(x1[k], w[k], a1);
            a2 = fmaf(x2[k], w[k], a2);
            a3 = fmaf(x3[k], w[k], a3);
        }
        Y[(size_t)(node + 0) * N_CLS + lane] = a0 * nrm[node + 0];
        Y[(size_t)(node + 1) * N_CLS + lane] = a1 * nrm[node + 1];
        Y[(size_t)(node + 2) * N_CLS + lane] = a2 * nrm[node + 2];
        Y[(size_t)(node + 3) * N_CLS + lane] = a3 * nrm[node + 3];
    }
    for (; node < nend; ++node) {  // tail (absent when n % 16 == 0)
        const float* x0 = X + (size_t)node * N_FEAT;
        float a0 = 0.f;
#pragma unroll
        for (int k = 0; k < N_FEAT; ++k) a0 = fmaf(x0[k], w[k], a0);
        Y[(size_t)node * N_CLS + lane] = a0 * nrm[node];
    }
}

// 5) wave-per-dst-node gather, 4 edge-slots x 16 lanes, float4/lane, unroll x2:
//    out[n][c] = nrm[n] * sum_{e into n} Y[esrc[e]][c] + b[c]
__global__ __launch_bounds__(256) void k_agg(const int* __restrict__ off,
                                             const int* __restrict__ esrc,
                                             const float* __restrict__ Y,
                                             const float* __restrict__ nrm,
                                             const float* __restrict__ b,
                                             float* __restrict__ out, int n) {
    int wid = (int)((blockIdx.x * (size_t)blockDim.x + threadIdx.x) >> 6);
    if (wid >= n) return;
    int lane = threadIdx.x & 63;
    int g = lane >> 4;        // edge slot 0..3
    int c = (lane & 15) * 4;  // column base (16 lanes x float4 = full 64-col row)
    int s = off[wid];
    int e = off[wid + 1];
    float4 a0 = make_float4(0.f, 0.f, 0.f, 0.f);
    float4 a1 = make_float4(0.f, 0.f, 0.f, 0.f);
    int p = s + g;
    for (; p + 4 < e; p += 8) {
        int s0 = esrc[p];
        int s1 = esrc[p + 4];
        float4 r0 = *(const float4*)(Y + (size_t)s0 * N_CLS + c);
        float4 r1 = *(const float4*)(Y + (size_t)s1 * N_CLS + c);
        a0.x += r0.x; a0.y += r0.y; a0.z += r0.z; a0.w += r0.w;
        a1.x += r1.x; a1.y += r1.y; a1.z += r1.z; a1.w += r1.w;
    }
    if (p < e) {
        int s0 = esrc[p];
        float4 r0 = *(const float4*)(Y + (size_t)s0 * N_CLS + c);
        a0.x += r0.x; a0.y += r0.y; a0.z += r0.z; a0.w += r0.w;
    }
    a0.x += a1.x; a0.y += a1.y; a0.z += a1.z; a0.w += a1.w;
#pragma unroll
    for (int m = 16; m <= 32; m <<= 1) {
        a0.x += __shfl_xor(a0.x, m);
        a0.y += __shfl_xor(a0.y, m);
        a0.z += __shfl_xor(a0.z, m);
        a0.w += __shfl_xor(a0.w, m);
    }
    if (lane < 16) {
        float nv = nrm[wid];
        float4 bv = *(const float4*)(b + c);
        float4 o;
        o.x = a0.x * nv + bv.x;
        o.y = a0.y * nv + bv.y;
        o.z = a0.z * nv + bv.z;
        o.w = a0.w * nv + bv.w;
        *(float4*)(out + (size_t)wid * N_CLS + c) = o;
    }
}

extern "C" void kernel_launch(void* const* d_in, const int* in_sizes, int n_in,
                              void* d_out, int out_size, void* d_ws, size_t ws_size,
                              hipStream_t stream) {
    const float* X = (const float*)d_in[0];
    const float* W = (const float*)d_in[1];
    const float* b = (const float*)d_in[2];
    const int* src = (const int*)d_in[3];
    const int* dst = (const int*)d_in[4];
    int n = in_sizes[0] / N_FEAT;
    int ne = in_sizes[3];
    float* out = (float*)d_out;

    char* w = (char*)d_ws;
    auto take = [&](size_t bytes) {
        char* p = w;
        w += (bytes + 255) & ~(size_t)255;
        return p;
    };
    int nb = (n + 255) / 256;
    int* deg = (int*)take((size_t)n * 4);
    int* off = (int*)take((size_t)(n + 1) * 4);
    int* rank = (int*)take((size_t)ne * 4);
    int* offtmp = (int*)take((size_t)n * 4);
    int* bsum = (int*)take((size_t)nb * 4);
    int* esrc = (int*)take((size_t)ne * 4);
    float* nrm = (float*)take((size_t)n * 4);
    float* Y = (float*)take((size_t)n * N_CLS * 4);

    hipMemsetAsync(deg, 0, (size_t)n * 4, stream);

    const int tb = 256;
    k_rank<<<(ne + tb - 1) / tb, tb, 0, stream>>>(dst, ne, deg, rank);
    k_scan1<<<nb, 256, 0, stream>>>(deg, n, offtmp, bsum);
    k_scan2<<<1, 1024, 0, stream>>>(bsum, nb);
    k_scan3<<<nb, 256, 0, stream>>>(deg, offtmp, bsum, n, ne, off, nrm);
    k_scatter<<<(ne + tb - 1) / tb, tb, 0, stream>>>(src, dst, rank, ne, off, esrc);
    long long gemm_waves = (n + NODES_PER_WAVE - 1) / NODES_PER_WAVE;
    long long gemm_threads = gemm_waves * 64;
    k_gemm<<<(int)((gemm_threads + tb - 1) / tb), tb, 0, stream>>>(X, W, nrm, Y, n);
    long long total_threads = (long long)n * 64;
    k_agg<<<(int)((total_threads + tb - 1) / tb), tb, 0, stream>>>(off, esrc, Y, nrm, b, out, n);
}

// Round 8
// 116.864 us; speedup vs baseline: 1.8583x; 1.8583x over previous
//
#include <hip/hip_runtime.h>

#define N_FEAT 128
#define N_CLS 64

// 1) degree histogram over dst + per-edge rank (coalesced store, 1 atomic/edge)
__global__ __launch_bounds__(256) void k_rank(const int* __restrict__ dst, int ne,
                                              int* __restrict__ deg, int* __restrict__ rank) {
    int i = blockIdx.x * blockDim.x + threadIdx.x;
    if (i < ne) rank[i] = atomicAdd(&deg[dst[i]], 1);
}

// 2a) per-block exclusive scan of deg (256 elems/block), emit block sums
__global__ __launch_bounds__(256) void k_scan1(const int* __restrict__ deg, int n,
                                               int* __restrict__ offtmp, int* __restrict__ bsum) {
    __shared__ int s[256];
    int t = threadIdx.x;
    int i = blockIdx.x * 256 + t;
    int v = (i < n) ? deg[i] : 0;
    s[t] = v;
    __syncthreads();
    for (int d = 1; d < 256; d <<= 1) {
        int u = (t >= d) ? s[t - d] : 0;
        __syncthreads();
        s[t] += u;
        __syncthreads();
    }
    if (i < n) offtmp[i] = s[t] - v;  // exclusive
    if (t == 255) bsum[blockIdx.x] = s[255];
}

// 2b) single tiny block: exclusive scan of block sums (nb <= 1024)
__global__ __launch_bounds__(1024) void k_scan2(int* __restrict__ bsum, int nb) {
    __shared__ int s[1024];
    int t = threadIdx.x;
    int v = (t < nb) ? bsum[t] : 0;
    s[t] = v;
    __syncthreads();
    for (int d = 1; d < 1024; d <<= 1) {
        int u = (t >= d) ? s[t - d] : 0;
        __syncthreads();
        s[t] += u;
        __syncthreads();
    }
    if (t < nb) bsum[t] = s[t] - v;  // exclusive
}

// 2c) finalize: off = offtmp + block offset; nrm = rsqrt(max(deg,1))
__global__ __launch_bounds__(256) void k_scan3(const int* __restrict__ deg,
                                               const int* __restrict__ offtmp,
                                               const int* __restrict__ bsum, int n, int ne,
                                               int* __restrict__ off, float* __restrict__ nrm) {
    int i = blockIdx.x * 256 + threadIdx.x;
    if (i < n) {
        off[i] = offtmp[i] + bsum[blockIdx.x];
        nrm[i] = rsqrtf(fmaxf((float)deg[i], 1.0f));
    }
    if (i == 0) off[n] = ne;  // total edge count is known
}

// 3) atomic-free scatter: esrc[off[dst] + rank] = src
__global__ __launch_bounds__(256) void k_scatter(const int* __restrict__ src,
                                                 const int* __restrict__ dst,
                                                 const int* __restrict__ rank, int ne,
                                                 const int* __restrict__ off,
                                                 int* __restrict__ esrc) {
    int i = blockIdx.x * blockDim.x + threadIdx.x;
    if (i < ne) {
        esrc[off[dst[i]] + rank[i]] = src[i];
    }
}

// 4) Y[node] = (X[node] * nrm[node]) @ W
//    Block = 4 waves; wave = one 16-col quarter (cq wave-uniform -> W addresses
//    SGPR-derived -> s_load K$ broadcast, proven in rounds 3/5 via SGPR=112).
//    lane = node. acc[16] (~32 VGPR). 782 blocks ~ 3/CU -> latency hidden.
//    Each lane's 16 outputs = one contiguous 64B sector (clean writes).
__global__ __launch_bounds__(256) void k_gemm(const float* __restrict__ X,
                                              const float* __restrict__ W,
                                              const float* __restrict__ nrm,
                                              float* __restrict__ Y, int n) {
    int lane = threadIdx.x & 63;
    int q = __builtin_amdgcn_readfirstlane(threadIdx.x >> 6);  // wave id 0..3
    int cq = q * 16;
    int node = blockIdx.x * 64 + lane;
    if (node >= n) return;

    float acc[16];
#pragma unroll
    for (int c = 0; c < 16; ++c) acc[c] = 0.f;

    const float* xrow = X + (size_t)node * N_FEAT;
    const float* wq = W + cq;
    for (int k4 = 0; k4 < N_FEAT; k4 += 4) {
        float4 xv = *(const float4*)(xrow + k4);
#pragma unroll
        for (int j = 0; j < 4; ++j) {
            float xj = (j == 0) ? xv.x : (j == 1) ? xv.y : (j == 2) ? xv.z : xv.w;
            const float* wrow = wq + (size_t)(k4 + j) * N_CLS;  // wave-uniform addr
#pragma unroll
            for (int c = 0; c < 16; c += 4) {
                float4 wv = *(const float4*)(wrow + c);
                acc[c + 0] = fmaf(xj, wv.x, acc[c + 0]);
                acc[c + 1] = fmaf(xj, wv.y, acc[c + 1]);
                acc[c + 2] = fmaf(xj, wv.z, acc[c + 2]);
                acc[c + 3] = fmaf(xj, wv.w, acc[c + 3]);
            }
        }
    }

    float nv = nrm[node];
    float* yrow = Y + (size_t)node * N_CLS + cq;
#pragma unroll
    for (int c = 0; c < 16; c += 4) {
        float4 o;
        o.x = acc[c + 0] * nv;
        o.y = acc[c + 1] * nv;
        o.z = acc[c + 2] * nv;
        o.w = acc[c + 3] * nv;
        *(float4*)(yrow + c) = o;
    }
}

// 5) wave-per-dst-node gather, 4 edge-slots x 16 lanes, float4/lane, unroll x2:
//    out[n][c] = nrm[n] * sum_{e into n} Y[esrc[e]][c] + b[c]
__global__ __launch_bounds__(256) void k_agg(const int* __restrict__ off,
                                             const int* __restrict__ esrc,
                                             const float* __restrict__ Y,
                                             const float* __restrict__ nrm,
                                             const float* __restrict__ b,
                                             float* __restrict__ out, int n) {
    int wid = (int)((blockIdx.x * (size_t)blockDim.x + threadIdx.x) >> 6);
    if (wid >= n) return;
    int lane = threadIdx.x & 63;
    int g = lane >> 4;        // edge slot 0..3
    int c = (lane & 15) * 4;  // column base (16 lanes x float4 = full 64-col row)
    int s = off[wid];
    int e = off[wid + 1];
    float4 a0 = make_float4(0.f, 0.f, 0.f, 0.f);
    float4 a1 = make_float4(0.f, 0.f, 0.f, 0.f);
    int p = s + g;
    for (; p + 4 < e; p += 8) {
        int s0 = esrc[p];
        int s1 = esrc[p + 4];
        float4 r0 = *(const float4*)(Y + (size_t)s0 * N_CLS + c);
        float4 r1 = *(const float4*)(Y + (size_t)s1 * N_CLS + c);
        a0.x += r0.x; a0.y += r0.y; a0.z += r0.z; a0.w += r0.w;
        a1.x += r1.x; a1.y += r1.y; a1.z += r1.z; a1.w += r1.w;
    }
    if (p < e) {
        int s0 = esrc[p];
        float4 r0 = *(const float4*)(Y + (size_t)s0 * N_CLS + c);
        a0.x += r0.x; a0.y += r0.y; a0.z += r0.z; a0.w += r0.w;
    }
    a0.x += a1.x; a0.y += a1.y; a0.z += a1.z; a0.w += a1.w;
#pragma unroll
    for (int m = 16; m <= 32; m <<= 1) {
        a0.x += __shfl_xor(a0.x, m);
        a0.y += __shfl_xor(a0.y, m);
        a0.z += __shfl_xor(a0.z, m);
        a0.w += __shfl_xor(a0.w, m);
    }
    if (lane < 16) {
        float nv = nrm[wid];
        float4 bv = *(const float4*)(b + c);
        float4 o;
        o.x = a0.x * nv + bv.x;
        o.y = a0.y * nv + bv.y;
        o.z = a0.z * nv + bv.z;
        o.w = a0.w * nv + bv.w;
        *(float4*)(out + (size_t)wid * N_CLS + c) = o;
    }
}

extern "C" void kernel_launch(void* const* d_in, const int* in_sizes, int n_in,
                              void* d_out, int out_size, void* d_ws, size_t ws_size,
                              hipStream_t stream) {
    const float* X = (const float*)d_in[0];
    const float* W = (const float*)d_in[1];
    const float* b = (const float*)d_in[2];
    const int* src = (const int*)d_in[3];
    const int* dst = (const int*)d_in[4];
    int n = in_sizes[0] / N_FEAT;
    int ne = in_sizes[3];
    float* out = (float*)d_out;

    char* w = (char*)d_ws;
    auto take = [&](size_t bytes) {
        char* p = w;
        w += (bytes + 255) & ~(size_t)255;
        return p;
    };
    int nb = (n + 255) / 256;
    int* deg = (int*)take((size_t)n * 4);
    int* off = (int*)take((size_t)(n + 1) * 4);
    int* rank = (int*)take((size_t)ne * 4);
    int* offtmp = (int*)take((size_t)n * 4);
    int* bsum = (int*)take((size_t)nb * 4);
    int* esrc = (int*)take((size_t)ne * 4);
    float* nrm = (float*)take((size_t)n * 4);
    float* Y = (float*)take((size_t)n * N_CLS * 4);

    hipMemsetAsync(deg, 0, (size_t)n * 4, stream);

    const int tb = 256;
    k_rank<<<(ne + tb - 1) / tb, tb, 0, stream>>>(dst, ne, deg, rank);
    k_scan1<<<nb, 256, 0, stream>>>(deg, n, offtmp, bsum);
    k_scan2<<<1, 1024, 0, stream>>>(bsum, nb);
    k_scan3<<<nb, 256, 0, stream>>>(deg, offtmp, bsum, n, ne, off, nrm);
    k_scatter<<<(ne + tb - 1) / tb, tb, 0, stream>>>(src, dst, rank, ne, off, esrc);
    int gemm_blocks = (n + 63) / 64;
    k_gemm<<<gemm_blocks, 256, 0, stream>>>(X, W, nrm, Y, n);
    long long total_threads = (long long)n * 64;
    k_agg<<<(int)((total_threads + tb - 1) / tb), tb, 0, stream>>>(off, esrc, Y, nrm, b, out, n);
}

// Round 9
// 116.185 us; speedup vs baseline: 1.8692x; 1.0058x over previous
//
#include <hip/hip_runtime.h>

#define N_FEAT 128
#define N_CLS 64

// 0) zero deg (the ROCm fillBuffer kernel costs 43us for 200KB; this is ~2us)
__global__ __launch_bounds__(256) void k_zero(int4* __restrict__ p, int n4) {
    int i = blockIdx.x * blockDim.x + threadIdx.x;
    if (i < n4) p[i] = make_int4(0, 0, 0, 0);
}

// 1) degree histogram over dst + per-edge rank (coalesced store, 1 atomic/edge)
__global__ __launch_bounds__(256) void k_rank(const int* __restrict__ dst, int ne,
                                              int* __restrict__ deg, int* __restrict__ rank) {
    int i = blockIdx.x * blockDim.x + threadIdx.x;
    if (i < ne) rank[i] = atomicAdd(&deg[dst[i]], 1);
}

// 2a) per-block exclusive scan of deg (256 elems/block), emit block sums
__global__ __launch_bounds__(256) void k_scan1(const int* __restrict__ deg, int n,
                                               int* __restrict__ offtmp, int* __restrict__ bsum) {
    __shared__ int s[256];
    int t = threadIdx.x;
    int i = blockIdx.x * 256 + t;
    int v = (i < n) ? deg[i] : 0;
    s[t] = v;
    __syncthreads();
    for (int d = 1; d < 256; d <<= 1) {
        int u = (t >= d) ? s[t - d] : 0;
        __syncthreads();
        s[t] += u;
        __syncthreads();
    }
    if (i < n) offtmp[i] = s[t] - v;  // exclusive
    if (t == 255) bsum[blockIdx.x] = s[255];
}

// 2b) single tiny block: exclusive scan of block sums (nb <= 1024)
__global__ __launch_bounds__(1024) void k_scan2(int* __restrict__ bsum, int nb) {
    __shared__ int s[1024];
    int t = threadIdx.x;
    int v = (t < nb) ? bsum[t] : 0;
    s[t] = v;
    __syncthreads();
    for (int d = 1; d < 1024; d <<= 1) {
        int u = (t >= d) ? s[t - d] : 0;
        __syncthreads();
        s[t] += u;
        __syncthreads();
    }
    if (t < nb) bsum[t] = s[t] - v;  // exclusive
}

// 2c) finalize: off = offtmp + block offset; nrm = rsqrt(max(deg,1))
__global__ __launch_bounds__(256) void k_scan3(const int* __restrict__ deg,
                                               const int* __restrict__ offtmp,
                                               const int* __restrict__ bsum, int n, int ne,
                                               int* __restrict__ off, float* __restrict__ nrm) {
    int i = blockIdx.x * 256 + threadIdx.x;
    if (i < n) {
        off[i] = offtmp[i] + bsum[blockIdx.x];
        nrm[i] = rsqrtf(fmaxf((float)deg[i], 1.0f));
    }
    if (i == 0) off[n] = ne;  // total edge count is known
}

// 3) atomic-free scatter: esrc[off[dst] + rank] = src
__global__ __launch_bounds__(256) void k_scatter(const int* __restrict__ src,
                                                 const int* __restrict__ dst,
                                                 const int* __restrict__ rank, int ne,
                                                 const int* __restrict__ off,
                                                 int* __restrict__ esrc) {
    int i = blockIdx.x * blockDim.x + threadIdx.x;
    if (i < ne) {
        esrc[off[dst[i]] + rank[i]] = src[i];
    }
}

// 4) Y[node] = (X[node] * nrm[node]) @ W
//    Block = 4 waves; wave = one 16-col quarter (cq wave-uniform -> W addresses
//    SGPR-derived -> s_load K$ broadcast). lane = node. acc[16].
__global__ __launch_bounds__(256) void k_gemm(const float* __restrict__ X,
                                              const float* __restrict__ W,
                                              const float* __restrict__ nrm,
                                              float* __restrict__ Y, int n) {
    int lane = threadIdx.x & 63;
    int q = __builtin_amdgcn_readfirstlane(threadIdx.x >> 6);  // wave id 0..3
    int cq = q * 16;
    int node = blockIdx.x * 64 + lane;
    if (node >= n) return;

    float acc[16];
#pragma unroll
    for (int c = 0; c < 16; ++c) acc[c] = 0.f;

    const float* xrow = X + (size_t)node * N_FEAT;
    const float* wq = W + cq;
    for (int k4 = 0; k4 < N_FEAT; k4 += 4) {
        float4 xv = *(const float4*)(xrow + k4);
#pragma unroll
        for (int j = 0; j < 4; ++j) {
            float xj = (j == 0) ? xv.x : (j == 1) ? xv.y : (j == 2) ? xv.z : xv.w;
            const float* wrow = wq + (size_t)(k4 + j) * N_CLS;  // wave-uniform addr
#pragma unroll
            for (int c = 0; c < 16; c += 4) {
                float4 wv = *(const float4*)(wrow + c);
                acc[c + 0] = fmaf(xj, wv.x, acc[c + 0]);
                acc[c + 1] = fmaf(xj, wv.y, acc[c + 1]);
                acc[c + 2] = fmaf(xj, wv.z, acc[c + 2]);
                acc[c + 3] = fmaf(xj, wv.w, acc[c + 3]);
            }
        }
    }

    float nv = nrm[node];
    float* yrow = Y + (size_t)node * N_CLS + cq;
#pragma unroll
    for (int c = 0; c < 16; c += 4) {
        float4 o;
        o.x = acc[c + 0] * nv;
        o.y = acc[c + 1] * nv;
        o.z = acc[c + 2] * nv;
        o.w = acc[c + 3] * nv;
        *(float4*)(yrow + c) = o;
    }
}

// 5) wave-per-dst-node gather, 4 edge-slots x 16 lanes, float4/lane, unroll x2:
//    out[n][c] = nrm[n] * sum_{e into n} Y[esrc[e]][c] + b[c]
__global__ __launch_bounds__(256) void k_agg(const int* __restrict__ off,
                                             const int* __restrict__ esrc,
                                             const float* __restrict__ Y,
                                             const float* __restrict__ nrm,
                                             const float* __restrict__ b,
                                             float* __restrict__ out, int n) {
    int wid = (int)((blockIdx.x * (size_t)blockDim.x + threadIdx.x) >> 6);
    if (wid >= n) return;
    int lane = threadIdx.x & 63;
    int g = lane >> 4;        // edge slot 0..3
    int c = (lane & 15) * 4;  // column base (16 lanes x float4 = full 64-col row)
    int s = off[wid];
    int e = off[wid + 1];
    float4 a0 = make_float4(0.f, 0.f, 0.f, 0.f);
    float4 a1 = make_float4(0.f, 0.f, 0.f, 0.f);
    int p = s + g;
    for (; p + 4 < e; p += 8) {
        int s0 = esrc[p];
        int s1 = esrc[p + 4];
        float4 r0 = *(const float4*)(Y + (size_t)s0 * N_CLS + c);
        float4 r1 = *(const float4*)(Y + (size_t)s1 * N_CLS + c);
        a0.x += r0.x; a0.y += r0.y; a0.z += r0.z; a0.w += r0.w;
        a1.x += r1.x; a1.y += r1.y; a1.z += r1.z; a1.w += r1.w;
    }
    if (p < e) {
        int s0 = esrc[p];
        float4 r0 = *(const float4*)(Y + (size_t)s0 * N_CLS + c);
        a0.x += r0.x; a0.y += r0.y; a0.z += r0.z; a0.w += r0.w;
    }
    a0.x += a1.x; a0.y += a1.y; a0.z += a1.z; a0.w += a1.w;
#pragma unroll
    for (int m = 16; m <= 32; m <<= 1) {
        a0.x += __shfl_xor(a0.x, m);
        a0.y += __shfl_xor(a0.y, m);
        a0.z += __shfl_xor(a0.z, m);
        a0.w += __shfl_xor(a0.w, m);
    }
    if (lane < 16) {
        float nv = nrm[wid];
        float4 bv = *(const float4*)(b + c);
        float4 o;
        o.x = a0.x * nv + bv.x;
        o.y = a0.y * nv + bv.y;
        o.z = a0.z * nv + bv.z;
        o.w = a0.w * nv + bv.w;
        *(float4*)(out + (size_t)wid * N_CLS + c) = o;
    }
}

extern "C" void kernel_launch(void* const* d_in, const int* in_sizes, int n_in,
                              void* d_out, int out_size, void* d_ws, size_t ws_size,
                              hipStream_t stream) {
    const float* X = (const float*)d_in[0];
    const float* W = (const float*)d_in[1];
    const float* b = (const float*)d_in[2];
    const int* src = (const int*)d_in[3];
    const int* dst = (const int*)d_in[4];
    int n = in_sizes[0] / N_FEAT;
    int ne = in_sizes[3];
    float* out = (float*)d_out;

    char* w = (char*)d_ws;
    auto take = [&](size_t bytes) {
        char* p = w;
        w += (bytes + 255) & ~(size_t)255;
        return p;
    };
    int nb = (n + 255) / 256;
    int* deg = (int*)take(((size_t)n + 4) * 4);  // padded to int4 multiple
    int* off = (int*)take((size_t)(n + 1) * 4);
    int* rank = (int*)take((size_t)ne * 4);
    int* offtmp = (int*)take((size_t)n * 4);
    int* bsum = (int*)take((size_t)nb * 4);
    int* esrc = (int*)take((size_t)ne * 4);
    float* nrm = (float*)take((size_t)n * 4);
    float* Y = (float*)take((size_t)n * N_CLS * 4);

    const int tb = 256;
    int n4 = (n + 3) / 4;
    k_zero<<<(n4 + tb - 1) / tb, tb, 0, stream>>>((int4*)deg, n4);
    k_rank<<<(ne + tb - 1) / tb, tb, 0, stream>>>(dst, ne, deg, rank);
    k_scan1<<<nb, 256, 0, stream>>>(deg, n, offtmp, bsum);
    k_scan2<<<1, 1024, 0, stream>>>(bsum, nb);
    k_scan3<<<nb, 256, 0, stream>>>(deg, offtmp, bsum, n, ne, off, nrm);
    k_scatter<<<(ne + tb - 1) / tb, tb, 0, stream>>>(src, dst, rank, ne, off, esrc);
    int gemm_blocks = (n + 63) / 64;
    k_gemm<<<gemm_blocks, 256, 0, stream>>>(X, W, nrm, Y, n);
    long long total_threads = (long long)n * 64;
    k_agg<<<(int)((total_threads + tb - 1) / tb), tb, 0, stream>>>(off, esrc, Y, nrm, b, out, n);
}